// Round 6
// baseline (1062.838 us; speedup 1.0000x reference)
//
#include <hip/hip_runtime.h>
#include <math.h>

// ---------------------------------------------------------------------------
// Dual CTC loss forward, linear-probability fp64 recursion, beta-normalized
// B/L split form.
//  error task:   B=32, T=2000, C=4,  S=50   (1 pair per lane)
//  phoneme task: B=32, T=2000, C=64, S=200  (4 pairs per lane)
// R6: beta = alpha / prod_t pb(t):
//   B'[s] = B[s] + L[s-1]                       (1 f64 add, mul-free)
//   L'[s] = r_s * (B[s] + L[s] + skip_s*L[s-1]) (r_s = p_s/pb, from gather)
//   loss  = K*ln2 - ln(beta_read) - Spb,  Spb = sum_{t<len} ln pb(t)
//   (Spb computed in the parallel gather via per-row atomicAdd)
// Prefetch: two 16-row register buffers; all 16 next-group loads issued
// then sched_barrier(0) so the scheduler cannot sink them to use sites
// (R4/R5 VGPR_Count=56/36 proved the compiler collapses per-step rings).
// Renorm every 16 steps pinned to ~2^500; d clamped both directions since
// beta can grow. Falls back to the R2 proven path if ws too small.
// ---------------------------------------------------------------------------

static constexpr float  LOG2E = 1.4426950408889634f;
static constexpr double LN2D  = 0.6931471805599453;

#define DPP_WAVE_SHR1   0x138
#define DPP_ROW_SHR(n)  (0x110 | (n))
#define DPP_ROW_BCAST15 0x142
#define DPP_ROW_BCAST31 0x143

__device__ __forceinline__ float fexp2(float x) {
  return __builtin_amdgcn_exp2f(x);
}
__device__ __forceinline__ float flog2(float x) {
  return __builtin_amdgcn_logf(x);
}

// prev-lane value (lane i gets lane i-1; lane 0 gets 0.0) — pure VALU
__device__ __forceinline__ double dpp_shr1_f64(double x) {
  int lo = __double2loint(x), hi = __double2hiint(x);
  lo = __builtin_amdgcn_update_dpp(0, lo, DPP_WAVE_SHR1, 0xf, 0xf, true);
  hi = __builtin_amdgcn_update_dpp(0, hi, DPP_WAVE_SHR1, 0xf, 0xf, true);
  return __hiloint2double(hi, lo);
}

__device__ __forceinline__ int imax2(int a, int b) { return a > b ? a : b; }

__device__ __forceinline__ int wave_imax(int v) {
  v = imax2(v, __builtin_amdgcn_update_dpp(0, v, DPP_ROW_SHR(1), 0xf, 0xf, true));
  v = imax2(v, __builtin_amdgcn_update_dpp(0, v, DPP_ROW_SHR(2), 0xf, 0xf, true));
  v = imax2(v, __builtin_amdgcn_update_dpp(0, v, DPP_ROW_SHR(4), 0xf, 0xf, true));
  v = imax2(v, __builtin_amdgcn_update_dpp(0, v, DPP_ROW_SHR(8), 0xf, 0xf, true));
  v = imax2(v, __builtin_amdgcn_update_dpp(0, v, DPP_ROW_BCAST15, 0xf, 0xf, true));
  v = imax2(v, __builtin_amdgcn_update_dpp(0, v, DPP_ROW_BCAST31, 0xf, 0xf, true));
  return __builtin_amdgcn_readlane(v, 63);
}

static constexpr int GROWS = 2032;  // padded rows (prefetch overruns len)

// ========================= fast path =======================================

// merged gather: z=0 phoneme (C=64), z=1 error (C=4).
// Writes r = p_class/p_blank per extended label slot, and accumulates
// Spb[chain] += log2(pb) for t < len (parallel masked reduction).
__global__ __launch_bounds__(256) void gather_all_kernel(
    const float* __restrict__ ph_logits, const float* __restrict__ err_logits,
    const int* __restrict__ ph_tgt, const int* __restrict__ err_tgt,
    const int* __restrict__ ph_il, const int* __restrict__ err_il,
    float* __restrict__ Gph, float* __restrict__ Ger,
    float* __restrict__ Spb) {
  const int lane = threadIdx.x & 63;
  const int t = blockIdx.x * 4 + (threadIdx.x >> 6);
  const int b = blockIdx.y;
  if (blockIdx.z == 0) {
    // ---- phoneme ----
    const float z = ph_logits[((size_t)b * 2000 + t) * 64 + lane] * LOG2E;
    float m = z;
#pragma unroll
    for (int off = 32; off >= 1; off >>= 1) m = fmaxf(m, __shfl_xor(m, off, 64));
    const float zm = z - m;
    const float e = fexp2(zm);
    float s = e;
#pragma unroll
    for (int off = 32; off >= 1; off >>= 1) s += __shfl_xor(s, off, 64);
    const int ei = __float_as_int(e);
    const float e0 = __int_as_float(__builtin_amdgcn_readlane(ei, 0));
    const float inv0 = 1.0f / e0;  // r = e_cls / e_blank
    const int* tb = ph_tgt + b * 200;
    float o[4];
#pragma unroll
    for (int k = 0; k < 4; ++k) {
      const int si = lane * 4 + k;
      const int cls = (si < 200) ? tb[si] : 0;
      const float v = __int_as_float(__builtin_amdgcn_ds_bpermute(cls << 2, ei));
      o[k] = (si < 200) ? (v * inv0) : 0.0f;
    }
    *(float4*)(Gph + ((size_t)b * GROWS + t) * 256 + lane * 4) =
        make_float4(o[0], o[1], o[2], o[3]);
    if (lane == 0 && t < ph_il[b]) {
      // log2(pb) = (z0 - m) - log2(sum)
      atomicAdd(Spb + 32 + b, zm - flog2(s));
    }
  } else {
    // ---- error ----
    const float4 v = *(const float4*)(err_logits + ((size_t)b * 2000 + t) * 4);
    const float z0 = v.x * LOG2E, z1 = v.y * LOG2E, z2 = v.z * LOG2E,
                z3 = v.w * LOG2E;
    const float m = fmaxf(fmaxf(z0, z1), fmaxf(z2, z3));
    const float e0 = fexp2(z0 - m), e1 = fexp2(z1 - m);
    const float e2 = fexp2(z2 - m), e3 = fexp2(z3 - m);
    const int c1 = err_tgt[b * 50 + (lane < 50 ? lane : 49)];
    const float num = (c1 == 1) ? e1 : (c1 == 2) ? e2 : e3;
    const float r = (lane < 50) ? (num / e0) : 0.0f;
    Ger[((size_t)b * GROWS + t) * 64 + lane] = r;
    if (lane == 0 && t < err_il[b]) {
      atomicAdd(Spb + b, (z0 - m) - flog2(e0 + e1 + e2 + e3));
    }
  }
}

template <int P> struct RowP { float v[P]; };

template <int P>
__device__ __forceinline__ RowP<P> load_rowp(const float* p) {
  RowP<P> r;
  if constexpr (P == 4) {
    const float4 a = *(const float4*)p;
    r.v[0] = a.x; r.v[1] = a.y; r.v[2] = a.z; r.v[3] = a.w;
  } else {
    r.v[0] = *p;
  }
  return r;
}

template <int P>
__device__ __forceinline__ void bl_renorm(double (&B)[P], double (&L)[P],
                                          int& K) {
  double mm = B[0];
#pragma unroll
  for (int k = 0; k < P; ++k) mm = fmax(fmax(mm, B[k]), L[k]);
  const int ex = (__double2hiint(mm) >> 20) & 0x7ff;
  const int emax = wave_imax(ex);
  if (emax > 0) {
    int d = 1523 - emax;            // pin band max to ~2^500
    if (d > 1023) d = 1023;         // keep 2^d normal (both directions:
    if (d < -1022) d = -1022;       //  beta can grow in this formulation)
    const double sc = __hiloint2double((d + 1023) << 20, 0);
#pragma unroll
    for (int k = 0; k < P; ++k) { B[k] *= sc; L[k] *= sc; }
    K += d;
  }
}

template <int P>
__device__ __forceinline__ void bl_step(double (&B)[P], double (&L)[P],
                                        const double (&skipm)[P],
                                        const RowP<P>& f) {
  const double Lm1 = dpp_shr1_f64(L[P - 1]);
  double nB[P], nL[P];
#pragma unroll
  for (int k = 0; k < P; ++k) {
    const double Lp = (k >= 1) ? L[k - 1] : Lm1;
    nB[k] = B[k] + Lp;
    nL[k] = (double)f.v[k] * fma(skipm[k], Lp, B[k] + L[k]);
  }
#pragma unroll
  for (int k = 0; k < P; ++k) { B[k] = nB[k]; L[k] = nL[k]; }
}

// One wave advances one chain; lane owns pairs s = lane*P..lane*P+P-1.
template <int P, int S>
__device__ __forceinline__ void chain_bl2(
    const float* __restrict__ Glab,  // [GROWS][64*P] r-values
    const int* __restrict__ tb, int len, int tl, float spb,
    float* __restrict__ out, double* sa) {
  constexpr int LSTRIDE = 64 * P;
  const int lane = threadIdx.x;

  double skipm[P];
#pragma unroll
  for (int k = 0; k < P; ++k) {
    const int s = lane * P + k;
    skipm[k] = (s >= 1 && s < S && tb[s] != tb[s - 1]) ? 1.0 : 0.0;
  }

  double B[P], L[P];
#pragma unroll
  for (int k = 0; k < P; ++k) { B[k] = 0.0; L[k] = 0.0; }
  {
    const float r0 = Glab[0];  // lane0 slot0 = r_{tgt[0]}(0)
    if (lane == 0) { B[0] = 1.0; L[0] = (double)r0; }
  }
  int K = 0;

  const float* Gl = Glab + lane * P;

  // double-buffered 16-row groups; loads batched + sched_barrier so the
  // scheduler cannot sink them (issue->use distance >= 16 steps)
  RowP<P> bufA[16], bufB[16];
#pragma unroll
  for (int u = 0; u < 16; ++u)
    bufA[u] = load_rowp<P>(Gl + (size_t)(1 + u) * LSTRIDE);
  __builtin_amdgcn_sched_barrier(0);

  const int tmain = 1 + ((len - 1) & ~31);
  int base = 1;
  for (; base < tmain; base += 32) {
    // phase A: load rows base+16..base+31 into B, consume A
    bl_renorm<P>(B, L, K);
#pragma unroll
    for (int u = 0; u < 16; ++u)
      bufB[u] = load_rowp<P>(Gl + (size_t)(base + 16 + u) * LSTRIDE);
    __builtin_amdgcn_sched_barrier(0);
#pragma unroll
    for (int u = 0; u < 16; ++u) bl_step<P>(B, L, skipm, bufA[u]);
    // phase B: load rows base+32..base+47 into A, consume B
    bl_renorm<P>(B, L, K);
#pragma unroll
    for (int u = 0; u < 16; ++u)
      bufA[u] = load_rowp<P>(Gl + (size_t)(base + 32 + u) * LSTRIDE);
    __builtin_amdgcn_sched_barrier(0);
#pragma unroll
    for (int u = 0; u < 16; ++u) bl_step<P>(B, L, skipm, bufB[u]);
  }
  // tail (< 32 steps, direct loads, renorm kept on the same cadence)
  for (int t = tmain; t < len; ++t) {
    if (((t - 1) & 15) == 0) bl_renorm<P>(B, L, K);
    const RowP<P> f = load_rowp<P>(Gl + (size_t)t * LSTRIDE);
    bl_step<P>(B, L, skipm, f);
  }

  // readout: alpha[2tl-1] = L[tl-1], alpha[2tl] = B[tl]
  double* saB = sa;
  double* saL = sa + 64 * P;
#pragma unroll
  for (int k = 0; k < P; ++k) {
    saB[lane * P + k] = B[k];
    saL[lane * P + k] = L[k];
  }
  __syncthreads();
  if (lane == 0) {
    const double a = saL[tl - 1] + saB[tl];
    // ln alpha = (ln stored - K ln2) + spb*ln2 ; loss = -ln alpha
    float loss = (float)((double)K * LN2D - log(a) - (double)spb * LN2D);
    if (!(loss < 1e29f)) loss = 0.f;  // zero_infinity
    atomicAdd(out, loss / ((float)tl * 32.0f));
  }
}

__global__ __launch_bounds__(64, 1) void ctc_chains_bl2_kernel(
    const float* __restrict__ Gph, const float* __restrict__ Ger,
    const float* __restrict__ Spb,
    const int* __restrict__ err_tgt, const int* __restrict__ ph_tgt,
    const int* __restrict__ err_il, const int* __restrict__ ph_il,
    const int* __restrict__ err_tl, const int* __restrict__ ph_tl,
    float* __restrict__ out) {
  __shared__ double sa[512];
  const int blk = blockIdx.x;
  if (blk < 32) {
    int len = err_il[blk]; if (len > 2000) len = 2000;
    chain_bl2<1, 50>(Ger + (size_t)blk * GROWS * 64, err_tgt + blk * 50, len,
                     err_tl[blk], Spb[blk], out, sa);
  } else {
    const int b = blk - 32;
    int len = ph_il[b]; if (len > 2000) len = 2000;
    chain_bl2<4, 200>(Gph + (size_t)b * GROWS * 256, ph_tgt + b * 200, len,
                      ph_tl[b], Spb[32 + b], out, sa);
  }
}

// ========================= fallback path (R2, proven) ======================

__global__ __launch_bounds__(256) void softmax4_kernel(
    const float* __restrict__ x, float* __restrict__ p, int nrows) {
  int r = blockIdx.x * blockDim.x + threadIdx.x;
  if (r >= nrows) return;
  float4 v = *reinterpret_cast<const float4*>(x + (size_t)r * 4);
  float z0 = v.x * LOG2E, z1 = v.y * LOG2E, z2 = v.z * LOG2E, z3 = v.w * LOG2E;
  float m = fmaxf(fmaxf(z0, z1), fmaxf(z2, z3));
  float e0 = fexp2(z0 - m), e1 = fexp2(z1 - m);
  float e2 = fexp2(z2 - m), e3 = fexp2(z3 - m);
  float inv = 1.0f / (e0 + e1 + e2 + e3);
  float4 o;
  o.x = e0 * inv; o.y = e1 * inv; o.z = e2 * inv; o.w = e3 * inv;
  *reinterpret_cast<float4*>(p + (size_t)r * 4) = o;
}

__global__ __launch_bounds__(256) void softmax64_kernel(
    const float* __restrict__ x, float* __restrict__ p, int nrows) {
  int row = blockIdx.x * 4 + (threadIdx.x >> 6);
  int lane = threadIdx.x & 63;
  if (row >= nrows) return;
  float z = x[(size_t)row * 64 + lane] * LOG2E;
  float m = z;
#pragma unroll
  for (int off = 32; off >= 1; off >>= 1) m = fmaxf(m, __shfl_xor(m, off, 64));
  float e = fexp2(z - m);
  float s = e;
#pragma unroll
  for (int off = 32; off >= 1; off >>= 1) s += __shfl_xor(s, off, 64);
  p[(size_t)row * 64 + lane] = e * (1.0f / s);
}

template <int C, int S, int R>
__device__ __forceinline__ void ctc_chain_lin_fb(
    const float* __restrict__ p_b, const int* __restrict__ tgt_b,
    int len, int tl, float* __restrict__ out, double* sa) {
  constexpr int L = 2 * S + 1;
  const int lane = threadIdx.x;
  int idx[R];
  double skipm[R];
#pragma unroll
  for (int j = 0; j < R; ++j) {
    const int l = lane * R + j;
    int cls = 0;
    bool sk = false;
    if (l & 1) {
      const int s = (l - 1) >> 1;
      const int sc = (s < S) ? s : (S - 1);
      cls = tgt_b[sc];
      if (s >= 1 && s < S) sk = (cls != tgt_b[s - 1]);
    }
    idx[j] = cls * 4;
    skipm[j] = sk ? 1.0 : 0.0;
  }
  double alpha[R];
#pragma unroll
  for (int j = 0; j < R; ++j) {
    const int l = lane * R + j;
    alpha[j] = (l <= 1) ? (double)p_b[idx[j] >> 2] : 0.0;
  }
  int K = 0;
  const int cl = lane & (C - 1);
  float rv = p_b[(size_t)((1 < len - 1) ? 1 : (len - 1)) * C + cl];
  float pf[R];
#pragma unroll
  for (int j = 0; j < R; ++j)
    pf[j] = __int_as_float(__builtin_amdgcn_ds_bpermute(idx[j], __float_as_int(rv)));
  rv = p_b[(size_t)((2 < len - 1) ? 2 : (len - 1)) * C + cl];
  for (int t = 1; t < len; ++t) {
    if ((t & 31) == 0) {
      double m = alpha[0];
#pragma unroll
      for (int j = 1; j < R; ++j) m = fmax(m, alpha[j]);
#pragma unroll
      for (int off = 1; off < 64; off <<= 1) m = fmax(m, __shfl_xor(m, off, 64));
      const long long bits = __double_as_longlong(m);
      const int e = (int)((bits >> 52) & 0x7FF);
      if (e > 0) {
        const double sc = __longlong_as_double((long long)(2046 - e) << 52);
#pragma unroll
        for (int j = 0; j < R; ++j) alpha[j] *= sc;
        K += 1023 - e;
      }
    }
    const int tn = (t + 2 < len) ? (t + 2) : (len - 1);
    const float rvn = p_b[(size_t)tn * C + cl];
    float pfn[R];
#pragma unroll
    for (int j = 0; j < R; ++j)
      pfn[j] = __int_as_float(__builtin_amdgcn_ds_bpermute(idx[j], __float_as_int(rv)));
    double am1 = __shfl_up(alpha[R - 1], 1, 64);
    double am2 = __shfl_up(alpha[R - 2], 1, 64);
    if (lane == 0) { am1 = 0.0; am2 = 0.0; }
    double na[R];
#pragma unroll
    for (int j = 0; j < R; ++j) {
      const double a0 = alpha[j];
      const double a1 = (j >= 1) ? alpha[j - 1] : am1;
      const double a2 = (j >= 2) ? alpha[j - 2] : ((j == 1) ? am1 : am2);
      double s = a0 + a1;
      s = fma(skipm[j], a2, s);
      na[j] = (double)pf[j] * s;
    }
#pragma unroll
    for (int j = 0; j < R; ++j) alpha[j] = na[j];
#pragma unroll
    for (int j = 0; j < R; ++j) pf[j] = pfn[j];
    rv = rvn;
  }
#pragma unroll
  for (int j = 0; j < R; ++j) {
    const int l = lane * R + j;
    if (l < L) sa[l] = alpha[j];
  }
  __syncthreads();
  if (lane == 0) {
    const double a = sa[2 * tl - 1] + sa[2 * tl];
    float loss = (float)((double)K * LN2D - log(a));
    if (!(loss < 1e29f)) loss = 0.0f;
    atomicAdd(out, loss / ((float)tl * 32.0f));
  }
}

__global__ __launch_bounds__(64) void ctc_chains_fb_kernel(
    const float* __restrict__ p_err, const float* __restrict__ p_ph,
    const int* __restrict__ err_tgt, const int* __restrict__ ph_tgt,
    const int* __restrict__ err_il, const int* __restrict__ ph_il,
    const int* __restrict__ err_tl, const int* __restrict__ ph_tl,
    float* __restrict__ out) {
  __shared__ double sa[512];
  const int T = 2000;
  const int blk = blockIdx.x;
  if (blk < 32) {
    const int b = blk;
    int len = err_il[b]; if (len > T) len = T;
    ctc_chain_lin_fb<4, 50, 2>(p_err + (size_t)b * T * 4, err_tgt + b * 50, len,
                               err_tl[b], out, sa);
  } else {
    const int b = blk - 32;
    int len = ph_il[b]; if (len > T) len = T;
    ctc_chain_lin_fb<64, 200, 7>(p_ph + (size_t)b * T * 64, ph_tgt + b * 200,
                                 len, ph_tl[b], out, sa);
  }
}

// ========================= launch ==========================================

extern "C" void kernel_launch(void* const* d_in, const int* in_sizes, int n_in,
                              void* d_out, int out_size, void* d_ws,
                              size_t ws_size, hipStream_t stream) {
  const float* err_logits = (const float*)d_in[0];
  const float* ph_logits  = (const float*)d_in[1];
  const int* err_tgt = (const int*)d_in[2];
  const int* ph_tgt  = (const int*)d_in[3];
  const int* err_il  = (const int*)d_in[4];
  const int* ph_il   = (const int*)d_in[5];
  const int* err_tl  = (const int*)d_in[6];
  const int* ph_tl   = (const int*)d_in[7];
  float* out = (float*)d_out;

  const size_t gph = (size_t)32 * GROWS * 256;  // 66.6 MB
  const size_t ger = (size_t)32 * GROWS * 64;   // 16.6 MB
  const size_t need = (gph + ger + 64) * sizeof(float);

  hipMemsetAsync(d_out, 0, sizeof(float), stream);

  if (ws_size >= need) {
    float* Gph = (float*)d_ws;
    float* Ger = Gph + gph;
    float* Spb = Ger + ger;
    hipMemsetAsync(Spb, 0, 64 * sizeof(float), stream);
    dim3 grid(500, 32, 2);
    gather_all_kernel<<<grid, 256, 0, stream>>>(ph_logits, err_logits, ph_tgt,
                                                err_tgt, ph_il, err_il, Gph,
                                                Ger, Spb);
    ctc_chains_bl2_kernel<<<64, 64, 0, stream>>>(Gph, Ger, Spb, err_tgt,
                                                 ph_tgt, err_il, ph_il, err_tl,
                                                 ph_tl, out);
  } else {
    const int B = 32, T = 2000;
    const int rows = B * T;
    float* p_err = (float*)d_ws;
    float* p_ph  = p_err + (size_t)rows * 4;
    softmax4_kernel<<<(rows + 255) / 256, 256, 0, stream>>>(err_logits, p_err, rows);
    softmax64_kernel<<<(rows + 3) / 4, 256, 0, stream>>>(ph_logits, p_ph, rows);
    ctc_chains_fb_kernel<<<64, 64, 0, stream>>>(p_err, p_ph, err_tgt, ph_tgt,
                                                err_il, ph_il, err_tl, ph_tl, out);
  }
}

// Round 8
// 229.627 us; speedup vs baseline: 4.6285x; 4.6285x over previous
//
#include <hip/hip_runtime.h>
#include <math.h>

// ---------------------------------------------------------------------------
// Dual CTC loss forward, linear-probability fp64 recursion, beta-normalized
// B/L split form (validated R6), with LDS-DMA staged chain loop (R8).
//  error task:   B=32, T=2000, C=4,  S=50   (1 pair per lane)
//  phoneme task: B=32, T=2000, C=64, S=200  (4 pairs per lane)
// R8 = R7 with compile fixes:
//  - global_load_lds / s_waitcnt builtins need LITERAL immediates (parse-time
//    ICE check rejects template parameters) -> if constexpr dispatch and
//    precomputed simm16 constants.
//  - sched_barrier(0) fences around manual waitcnt so ds_reads can't be
//    hoisted above the vmcnt wait.
// Structure:
//  - gather: no atomics; log2(pb) -> Lpb[chain][t]; chains sum it in a
//    lane-parallel prologue.
//  - chain: rows staged global->LDS (1 instr/row), double-buffered 16-row
//    groups, manual vmcnt; single wave per block so no s_barrier needed.
// Falls back to the R2 proven path if ws too small.
// ---------------------------------------------------------------------------

static constexpr float  LOG2E = 1.4426950408889634f;
static constexpr double LN2D  = 0.6931471805599453;
static constexpr int GROWS = 2032;  // padded rows per chain

#define DPP_WAVE_SHR1   0x138
#define DPP_ROW_SHR(n)  (0x110 | (n))
#define DPP_ROW_BCAST15 0x142
#define DPP_ROW_BCAST31 0x143

__device__ __forceinline__ float fexp2(float x) {
  return __builtin_amdgcn_exp2f(x);
}
__device__ __forceinline__ float flog2(float x) {
  return __builtin_amdgcn_logf(x);
}

// prev-lane value (lane i gets lane i-1; lane 0 gets 0.0) — pure VALU
__device__ __forceinline__ double dpp_shr1_f64(double x) {
  int lo = __double2loint(x), hi = __double2hiint(x);
  lo = __builtin_amdgcn_update_dpp(0, lo, DPP_WAVE_SHR1, 0xf, 0xf, true);
  hi = __builtin_amdgcn_update_dpp(0, hi, DPP_WAVE_SHR1, 0xf, 0xf, true);
  return __hiloint2double(hi, lo);
}

__device__ __forceinline__ int imax2(int a, int b) { return a > b ? a : b; }

__device__ __forceinline__ int wave_imax(int v) {
  v = imax2(v, __builtin_amdgcn_update_dpp(0, v, DPP_ROW_SHR(1), 0xf, 0xf, true));
  v = imax2(v, __builtin_amdgcn_update_dpp(0, v, DPP_ROW_SHR(2), 0xf, 0xf, true));
  v = imax2(v, __builtin_amdgcn_update_dpp(0, v, DPP_ROW_SHR(4), 0xf, 0xf, true));
  v = imax2(v, __builtin_amdgcn_update_dpp(0, v, DPP_ROW_SHR(8), 0xf, 0xf, true));
  v = imax2(v, __builtin_amdgcn_update_dpp(0, v, DPP_ROW_BCAST15, 0xf, 0xf, true));
  v = imax2(v, __builtin_amdgcn_update_dpp(0, v, DPP_ROW_BCAST31, 0xf, 0xf, true));
  return __builtin_amdgcn_readlane(v, 63);
}

// async global->LDS DMA: lane i's bytes from per-lane g land at wave-uniform
// lds base + lane*SZ. vmcnt-tracked. Builtin needs literal size immediates.
template <int SZ>
__device__ __forceinline__ void dma(const float* g, float* l) {
  auto gp = (const __attribute__((address_space(1))) void*)g;
  auto lp = (__attribute__((address_space(3))) void*)l;
  if constexpr (SZ == 4) {
    __builtin_amdgcn_global_load_lds(gp, lp, 4, 0, 0);
  } else {
    __builtin_amdgcn_global_load_lds(gp, lp, 16, 0, 0);
  }
}

// s_waitcnt with literal simm16 (gfx9: vmcnt[3:0]=bits3:0, exp=bits6:4,
// lgkm=bits11:8, vmcnt[5:4]=bits15:14). sched_barrier fences stop the
// scheduler from moving ds_reads across the wait.
__device__ __forceinline__ void wait_vmcnt16() {
  __builtin_amdgcn_sched_barrier(0);
  __builtin_amdgcn_s_waitcnt(20336);  // vmcnt=16, exp=7, lgkm=15
  __builtin_amdgcn_sched_barrier(0);
}
__device__ __forceinline__ void wait_vmcnt0() {
  __builtin_amdgcn_sched_barrier(0);
  __builtin_amdgcn_s_waitcnt(3952);   // vmcnt=0, exp=7, lgkm=15
  __builtin_amdgcn_sched_barrier(0);
}

// ========================= fast path =======================================

// merged gather: z=0 phoneme (C=64, wave/row), z=1 error (C=4).
// Writes r = p_class/p_blank per label slot and log2(pb) per row (no atomics).
__global__ __launch_bounds__(256) void gather_all_kernel(
    const float* __restrict__ ph_logits, const float* __restrict__ err_logits,
    const int* __restrict__ ph_tgt, const int* __restrict__ err_tgt,
    float* __restrict__ Gph, float* __restrict__ Ger,
    float* __restrict__ Lpb_ph, float* __restrict__ Lpb_er) {
  const int lane = threadIdx.x & 63;
  const int t = blockIdx.x * 4 + (threadIdx.x >> 6);
  const int b = blockIdx.y;
  if (blockIdx.z == 0) {
    // ---- phoneme ----
    const float z = ph_logits[((size_t)b * 2000 + t) * 64 + lane] * LOG2E;
    float m = z;
#pragma unroll
    for (int off = 32; off >= 1; off >>= 1) m = fmaxf(m, __shfl_xor(m, off, 64));
    const float zm = z - m;
    const float e = fexp2(zm);
    float s = e;
#pragma unroll
    for (int off = 32; off >= 1; off >>= 1) s += __shfl_xor(s, off, 64);
    const int ei = __float_as_int(e);
    const float e0 = __int_as_float(__builtin_amdgcn_readlane(ei, 0));
    const float inv0 = 1.0f / e0;  // r = e_cls / e_blank
    const int* tb = ph_tgt + b * 200;
    float o[4];
#pragma unroll
    for (int k = 0; k < 4; ++k) {
      const int si = lane * 4 + k;
      const int cls = (si < 200) ? tb[si] : 0;
      const float v = __int_as_float(__builtin_amdgcn_ds_bpermute(cls << 2, ei));
      o[k] = (si < 200) ? (v * inv0) : 0.0f;
    }
    *(float4*)(Gph + ((size_t)b * GROWS + t) * 256 + lane * 4) =
        make_float4(o[0], o[1], o[2], o[3]);
    if (lane == 0)  // lane 0's class is blank: log2(pb) = (z0-m) - log2(sum)
      Lpb_ph[(size_t)b * GROWS + t] = zm - flog2(s);
  } else {
    // ---- error ----
    const float4 v = *(const float4*)(err_logits + ((size_t)b * 2000 + t) * 4);
    const float z0 = v.x * LOG2E, z1 = v.y * LOG2E, z2 = v.z * LOG2E,
                z3 = v.w * LOG2E;
    const float m = fmaxf(fmaxf(z0, z1), fmaxf(z2, z3));
    const float e0 = fexp2(z0 - m), e1 = fexp2(z1 - m);
    const float e2 = fexp2(z2 - m), e3 = fexp2(z3 - m);
    const int c1 = err_tgt[b * 50 + (lane < 50 ? lane : 49)];
    const float num = (c1 == 1) ? e1 : (c1 == 2) ? e2 : e3;
    Ger[((size_t)b * GROWS + t) * 64 + lane] = (lane < 50) ? (num / e0) : 0.0f;
    if (lane == 0)
      Lpb_er[(size_t)b * GROWS + t] = (z0 - m) - flog2(e0 + e1 + e2 + e3);
  }
}

template <int P> struct RowP { float v[P]; };

template <int P>
__device__ __forceinline__ RowP<P> load_rowp(const float* p) {
  RowP<P> r;
  if constexpr (P == 4) {
    const float4 a = *(const float4*)p;
    r.v[0] = a.x; r.v[1] = a.y; r.v[2] = a.z; r.v[3] = a.w;
  } else {
    r.v[0] = *p;
  }
  return r;
}

template <int P>
__device__ __forceinline__ void bl_renorm(double (&B)[P], double (&L)[P],
                                          int& K) {
  double mm = B[0];
#pragma unroll
  for (int k = 0; k < P; ++k) mm = fmax(fmax(mm, B[k]), L[k]);
  const int ex = (__double2hiint(mm) >> 20) & 0x7ff;
  const int emax = wave_imax(ex);
  if (emax > 0) {
    int d = 1523 - emax;            // pin band max to ~2^500
    if (d > 1023) d = 1023;         // keep 2^d normal (beta can grow too)
    if (d < -1022) d = -1022;
    const double sc = __hiloint2double((d + 1023) << 20, 0);
#pragma unroll
    for (int k = 0; k < P; ++k) { B[k] *= sc; L[k] *= sc; }
    K += d;
  }
}

template <int P>
__device__ __forceinline__ void bl_step(double (&B)[P], double (&L)[P],
                                        const double (&skipm)[P],
                                        const RowP<P>& f) {
  const double Lm1 = dpp_shr1_f64(L[P - 1]);
  double nB[P], nL[P];
#pragma unroll
  for (int k = 0; k < P; ++k) {
    const double Lp = (k >= 1) ? L[k - 1] : Lm1;
    nB[k] = B[k] + Lp;
    nL[k] = (double)f.v[k] * fma(skipm[k], Lp, B[k] + L[k]);
  }
#pragma unroll
  for (int k = 0; k < P; ++k) { B[k] = nB[k]; L[k] = nL[k]; }
}

// One wave advances one chain; lane owns pairs s = lane*P..lane*P+P-1.
// G rows staged via LDS DMA, double-buffered 16-row groups.
template <int P, int S>
__device__ __forceinline__ void chain_bl3(
    const float* __restrict__ Glab,  // [GROWS][64*P] r-values
    const float* __restrict__ Lpb,   // [GROWS] log2(pb)
    const int* __restrict__ tb, int len, int tl,
    float* __restrict__ out, double* sa, float* stage) {
  constexpr int LSTRIDE = 64 * P;  // floats per row
  const int lane = threadIdx.x;

  // spb = sum_{t<len} log2(pb(t)), lane-parallel coalesced sum
  float spb = 0.f;
  for (int t = lane; t < len; t += 64) spb += Lpb[t];
#pragma unroll
  for (int off = 32; off >= 1; off >>= 1) spb += __shfl_xor(spb, off, 64);

  double skipm[P];
#pragma unroll
  for (int k = 0; k < P; ++k) {
    const int s = lane * P + k;
    skipm[k] = (s >= 1 && s < S && tb[s] != tb[s - 1]) ? 1.0 : 0.0;
  }

  double B[P], L[P];
#pragma unroll
  for (int k = 0; k < P; ++k) { B[k] = 0.0; L[k] = 0.0; }
  {
    const float r0 = Glab[0];  // lane0 slot0 = r_{tgt[0]}(0)
    if (lane == 0) { B[0] = 1.0; L[0] = (double)r0; }
  }
  int K = 0;

  const int ngroups = (len - 1) / 16;  // full groups of rows 1+16g..16+16g
  auto issue_group = [&](int g, int buf) {
    const float* rb = Glab + (size_t)(1 + g * 16) * LSTRIDE + lane * P;
    float* lb = stage + (size_t)buf * 16 * LSTRIDE;
#pragma unroll
    for (int u = 0; u < 16; ++u)
      dma<P * 4>(rb + u * LSTRIDE, lb + u * LSTRIDE);
  };

  if (ngroups >= 1) issue_group(0, 0);
  if (ngroups >= 2) issue_group(1, 1);

  for (int g = 0; g < ngroups; ++g) {
    if (g + 1 < ngroups) wait_vmcnt16();  // group g resident
    else                 wait_vmcnt0();
    bl_renorm<P>(B, L, K);  // every 16 steps (R4/R5-proven cadence)
    const float* lb = stage + (size_t)(g & 1) * 16 * LSTRIDE + lane * P;
    RowP<P> c0 = load_rowp<P>(lb);
    RowP<P> c1 = load_rowp<P>(lb + LSTRIDE);
#pragma unroll
    for (int u = 0; u < 16; ++u) {
      RowP<P> c2 = c1;
      if (u + 2 < 16) c2 = load_rowp<P>(lb + (u + 2) * LSTRIDE);
      bl_step<P>(B, L, skipm, c0);
      c0 = c1; c1 = c2;
    }
    if (g + 2 < ngroups) issue_group(g + 2, g & 1);  // refill consumed buf
  }
  // tail (<16 steps): direct global loads
  for (int t = 1 + ngroups * 16; t < len; ++t) {
    if (((t - 1) & 15) == 0) bl_renorm<P>(B, L, K);
    const RowP<P> f = load_rowp<P>(Glab + (size_t)t * LSTRIDE + lane * P);
    bl_step<P>(B, L, skipm, f);
  }

  // readout: alpha[2tl-1] = L[tl-1], alpha[2tl] = B[tl]
  double* saB = sa;
  double* saL = sa + 64 * P;
#pragma unroll
  for (int k = 0; k < P; ++k) {
    saB[lane * P + k] = B[k];
    saL[lane * P + k] = L[k];
  }
  __syncthreads();
  if (lane == 0) {
    const double a = saL[tl - 1] + saB[tl];
    float loss = (float)((double)K * LN2D - log(a) - (double)spb * LN2D);
    if (!(loss < 1e29f)) loss = 0.f;  // zero_infinity
    atomicAdd(out, loss / ((float)tl * 32.0f));
  }
}

__global__ __launch_bounds__(64) void ctc_chains_dma_kernel(
    const float* __restrict__ Gph, const float* __restrict__ Ger,
    const float* __restrict__ Lpb_ph, const float* __restrict__ Lpb_er,
    const int* __restrict__ err_tgt, const int* __restrict__ ph_tgt,
    const int* __restrict__ err_il, const int* __restrict__ ph_il,
    const int* __restrict__ err_tl, const int* __restrict__ ph_tl,
    float* __restrict__ out) {
  __shared__ float stage[2 * 16 * 256];  // 32 KB (phoneme); error uses prefix
  __shared__ double sa[512];
  const int blk = blockIdx.x;
  if (blk < 32) {
    int len = err_il[blk]; if (len > 2000) len = 2000;
    chain_bl3<1, 50>(Ger + (size_t)blk * GROWS * 64,
                     Lpb_er + (size_t)blk * GROWS, err_tgt + blk * 50, len,
                     err_tl[blk], out, sa, stage);
  } else {
    const int b = blk - 32;
    int len = ph_il[b]; if (len > 2000) len = 2000;
    chain_bl3<4, 200>(Gph + (size_t)b * GROWS * 256,
                      Lpb_ph + (size_t)b * GROWS, ph_tgt + b * 200, len,
                      ph_tl[b], out, sa, stage);
  }
}

// ========================= fallback path (R2, proven) ======================

__global__ __launch_bounds__(256) void softmax4_kernel(
    const float* __restrict__ x, float* __restrict__ p, int nrows) {
  int r = blockIdx.x * blockDim.x + threadIdx.x;
  if (r >= nrows) return;
  float4 v = *reinterpret_cast<const float4*>(x + (size_t)r * 4);
  float z0 = v.x * LOG2E, z1 = v.y * LOG2E, z2 = v.z * LOG2E, z3 = v.w * LOG2E;
  float m = fmaxf(fmaxf(z0, z1), fmaxf(z2, z3));
  float e0 = fexp2(z0 - m), e1 = fexp2(z1 - m);
  float e2 = fexp2(z2 - m), e3 = fexp2(z3 - m);
  float inv = 1.0f / (e0 + e1 + e2 + e3);
  float4 o;
  o.x = e0 * inv; o.y = e1 * inv; o.z = e2 * inv; o.w = e3 * inv;
  *reinterpret_cast<float4*>(p + (size_t)r * 4) = o;
}

__global__ __launch_bounds__(256) void softmax64_kernel(
    const float* __restrict__ x, float* __restrict__ p, int nrows) {
  int row = blockIdx.x * 4 + (threadIdx.x >> 6);
  int lane = threadIdx.x & 63;
  if (row >= nrows) return;
  float z = x[(size_t)row * 64 + lane] * LOG2E;
  float m = z;
#pragma unroll
  for (int off = 32; off >= 1; off >>= 1) m = fmaxf(m, __shfl_xor(m, off, 64));
  float e = fexp2(z - m);
  float s = e;
#pragma unroll
  for (int off = 32; off >= 1; off >>= 1) s += __shfl_xor(s, off, 64);
  p[(size_t)row * 64 + lane] = e * (1.0f / s);
}

template <int C, int S, int R>
__device__ __forceinline__ void ctc_chain_lin_fb(
    const float* __restrict__ p_b, const int* __restrict__ tgt_b,
    int len, int tl, float* __restrict__ out, double* sa) {
  constexpr int L = 2 * S + 1;
  const int lane = threadIdx.x;
  int idx[R];
  double skipm[R];
#pragma unroll
  for (int j = 0; j < R; ++j) {
    const int l = lane * R + j;
    int cls = 0;
    bool sk = false;
    if (l & 1) {
      const int s = (l - 1) >> 1;
      const int sc = (s < S) ? s : (S - 1);
      cls = tgt_b[sc];
      if (s >= 1 && s < S) sk = (cls != tgt_b[s - 1]);
    }
    idx[j] = cls * 4;
    skipm[j] = sk ? 1.0 : 0.0;
  }
  double alpha[R];
#pragma unroll
  for (int j = 0; j < R; ++j) {
    const int l = lane * R + j;
    alpha[j] = (l <= 1) ? (double)p_b[idx[j] >> 2] : 0.0;
  }
  int K = 0;
  const int cl = lane & (C - 1);
  float rv = p_b[(size_t)((1 < len - 1) ? 1 : (len - 1)) * C + cl];
  float pf[R];
#pragma unroll
  for (int j = 0; j < R; ++j)
    pf[j] = __int_as_float(__builtin_amdgcn_ds_bpermute(idx[j], __float_as_int(rv)));
  rv = p_b[(size_t)((2 < len - 1) ? 2 : (len - 1)) * C + cl];
  for (int t = 1; t < len; ++t) {
    if ((t & 31) == 0) {
      double m = alpha[0];
#pragma unroll
      for (int j = 1; j < R; ++j) m = fmax(m, alpha[j]);
#pragma unroll
      for (int off = 1; off < 64; off <<= 1) m = fmax(m, __shfl_xor(m, off, 64));
      const long long bits = __double_as_longlong(m);
      const int e = (int)((bits >> 52) & 0x7FF);
      if (e > 0) {
        const double sc = __longlong_as_double((long long)(2046 - e) << 52);
#pragma unroll
        for (int j = 0; j < R; ++j) alpha[j] *= sc;
        K += 1023 - e;
      }
    }
    const int tn = (t + 2 < len) ? (t + 2) : (len - 1);
    const float rvn = p_b[(size_t)tn * C + cl];
    float pfn[R];
#pragma unroll
    for (int j = 0; j < R; ++j)
      pfn[j] = __int_as_float(__builtin_amdgcn_ds_bpermute(idx[j], __float_as_int(rv)));
    double am1 = __shfl_up(alpha[R - 1], 1, 64);
    double am2 = __shfl_up(alpha[R - 2], 1, 64);
    if (lane == 0) { am1 = 0.0; am2 = 0.0; }
    double na[R];
#pragma unroll
    for (int j = 0; j < R; ++j) {
      const double a0 = alpha[j];
      const double a1 = (j >= 1) ? alpha[j - 1] : am1;
      const double a2 = (j >= 2) ? alpha[j - 2] : ((j == 1) ? am1 : am2);
      double s = a0 + a1;
      s = fma(skipm[j], a2, s);
      na[j] = (double)pf[j] * s;
    }
#pragma unroll
    for (int j = 0; j < R; ++j) alpha[j] = na[j];
#pragma unroll
    for (int j = 0; j < R; ++j) pf[j] = pfn[j];
    rv = rvn;
  }
#pragma unroll
  for (int j = 0; j < R; ++j) {
    const int l = lane * R + j;
    if (l < L) sa[l] = alpha[j];
  }
  __syncthreads();
  if (lane == 0) {
    const double a = sa[2 * tl - 1] + sa[2 * tl];
    float loss = (float)((double)K * LN2D - log(a));
    if (!(loss < 1e29f)) loss = 0.0f;
    atomicAdd(out, loss / ((float)tl * 32.0f));
  }
}

__global__ __launch_bounds__(64) void ctc_chains_fb_kernel(
    const float* __restrict__ p_err, const float* __restrict__ p_ph,
    const int* __restrict__ err_tgt, const int* __restrict__ ph_tgt,
    const int* __restrict__ err_il, const int* __restrict__ ph_il,
    const int* __restrict__ err_tl, const int* __restrict__ ph_tl,
    float* __restrict__ out) {
  __shared__ double sa[512];
  const int T = 2000;
  const int blk = blockIdx.x;
  if (blk < 32) {
    const int b = blk;
    int len = err_il[b]; if (len > T) len = T;
    ctc_chain_lin_fb<4, 50, 2>(p_err + (size_t)b * T * 4, err_tgt + b * 50, len,
                               err_tl[b], out, sa);
  } else {
    const int b = blk - 32;
    int len = ph_il[b]; if (len > T) len = T;
    ctc_chain_lin_fb<64, 200, 7>(p_ph + (size_t)b * T * 64, ph_tgt + b * 200,
                                 len, ph_tl[b], out, sa);
  }
}

// ========================= launch ==========================================

extern "C" void kernel_launch(void* const* d_in, const int* in_sizes, int n_in,
                              void* d_out, int out_size, void* d_ws,
                              size_t ws_size, hipStream_t stream) {
  const float* err_logits = (const float*)d_in[0];
  const float* ph_logits  = (const float*)d_in[1];
  const int* err_tgt = (const int*)d_in[2];
  const int* ph_tgt  = (const int*)d_in[3];
  const int* err_il  = (const int*)d_in[4];
  const int* ph_il   = (const int*)d_in[5];
  const int* err_tl  = (const int*)d_in[6];
  const int* ph_tl   = (const int*)d_in[7];
  float* out = (float*)d_out;

  const size_t gph = (size_t)32 * GROWS * 256;  // 66.6 MB
  const size_t ger = (size_t)32 * GROWS * 64;   // 16.6 MB
  const size_t lpb = (size_t)32 * GROWS;        // per task
  const size_t need = (gph + ger + 2 * lpb) * sizeof(float);

  (void)hipMemsetAsync(d_out, 0, sizeof(float), stream);

  if (ws_size >= need) {
    float* Gph = (float*)d_ws;
    float* Ger = Gph + gph;
    float* Lpb_ph = Ger + ger;
    float* Lpb_er = Lpb_ph + lpb;
    dim3 grid(500, 32, 2);
    gather_all_kernel<<<grid, 256, 0, stream>>>(ph_logits, err_logits, ph_tgt,
                                                err_tgt, Gph, Ger, Lpb_ph,
                                                Lpb_er);
    ctc_chains_dma_kernel<<<64, 64, 0, stream>>>(Gph, Ger, Lpb_ph, Lpb_er,
                                                 err_tgt, ph_tgt, err_il,
                                                 ph_il, err_tl, ph_tl, out);
  } else {
    const int B = 32, T = 2000;
    const int rows = B * T;
    float* p_err = (float*)d_ws;
    float* p_ph  = p_err + (size_t)rows * 4;
    softmax4_kernel<<<(rows + 255) / 256, 256, 0, stream>>>(err_logits, p_err, rows);
    softmax64_kernel<<<(rows + 3) / 4, 256, 0, stream>>>(ph_logits, p_ph, rows);
    ctc_chains_fb_kernel<<<64, 64, 0, stream>>>(p_err, p_ph, err_tgt, ph_tgt,
                                                err_il, ph_il, err_tl, ph_tl, out);
  }
}